// Round 8
// baseline (11678.818 us; speedup 1.0000x reference)
//
#include <hip/hip_runtime.h>
#include <hip/hip_bf16.h>
#include <math.h>

#define NCLS 64
#define KS 5
#define DD 256
#define NQ 8192   // NCLS*128
#define KNB 10

// row index in x (element-row units) of query g
__device__ __forceinline__ int qrow(int g) { return (g >> 7) * 133 + KS + (g & 127); }

// dtype-flag dispatched load of x / tao. isf32==1 -> underlying fp32, else bf16 bits.
__device__ __forceinline__ float LX(const void* x, int isf32, long i) {
    if (isf32) return ((const float*)x)[i];
    unsigned int bits = ((unsigned int)((const unsigned short*)x)[i]) << 16;
    return __uint_as_float(bits);
}

__device__ __forceinline__ float blk_reduce_sum(float v, float* red) {
    int t = threadIdx.x;
    red[t] = v; __syncthreads();
    for (int off = 128; off > 0; off >>= 1) {
        if (t < off) red[t] += red[t + off];
        __syncthreads();
    }
    float r = red[0];
    __syncthreads();
    return r;
}

__device__ __forceinline__ float blk_reduce_max(float v, float* red) {
    int t = threadIdx.x;
    red[t] = v; __syncthreads();
    for (int off = 128; off > 0; off >>= 1) {
        if (t < off) red[t] = fmaxf(red[t], red[t + off]);
        __syncthreads();
    }
    float r = red[0];
    __syncthreads();
    return r;
}

// ---------- dtype detector ----------
__global__ void detect_kernel(const unsigned short* xu, int* flag) {
    __shared__ int red[64];
    int t = threadIdx.x; // 64 threads
    int weird = 0;
    for (int i = t; i < 2048; i += 64) {
        unsigned int bits = ((unsigned int)xu[i]) << 16;
        float v = __uint_as_float(bits);
        float a = fabsf(v);
        if (!(a < 1e4f) || (a != 0.f && a < 1e-10f)) weird++;
    }
    red[t] = weird; __syncthreads();
    if (t == 0) {
        int s = 0;
        for (int i = 0; i < 64; i++) s += red[i];
        *flag = (s > 64) ? 1 : 0;   // many wild half-words => buffer is fp32
    }
}

// ---------- K0: qInv[g] = 1/||query_g|| ----------
__global__ __launch_bounds__(256) void qinv_kernel(const void* x, const int* flag,
                                                   float* __restrict__ qInv) {
    __shared__ float red[256];
    int g = blockIdx.x, t = threadIdx.x;
    int isf32 = flag[0];
    float v = LX(x, isf32, (long)qrow(g) * DD + t);
    float n2 = blk_reduce_sum(v * v, red);
    if (t == 0) qInv[g] = 1.f / sqrtf(n2);
}

// ---------- K1: proto, pn, self_sim ----------
__global__ __launch_bounds__(256) void proto_kernel(const void* x, const int* flag,
                                                    float* proto, float* pn, float* selfs) {
    __shared__ float red[256];
    int c = blockIdx.x, t = threadIdx.x;
    int isf32 = flag[0];
    float s = 0.f;
    for (int j = 0; j < KS; j++) s += LX(x, isf32, (long)(c * 133 + j) * DD + t);
    float p = s / 5.0f;
    proto[c * DD + t] = p;
    float n2 = blk_reduce_sum(p * p, red);
    float pv = p / sqrtf(n2);
    pn[c * DD + t] = pv;
    float ss = blk_reduce_sum(pv * pv, red);
    if (t == 0) selfs[c] = ss;
}

// ---------- K2: pre_sim argmax per query ----------
__global__ __launch_bounds__(256) void presim_kernel(const void* x, const int* flag,
                                                     const float* __restrict__ qInv,
                                                     const float* __restrict__ pn,
                                                     float* pre_max, int* pre_label) {
    __shared__ float qs[256];
    __shared__ float part[256];
    __shared__ float sims[64];
    int g = blockIdx.x, t = threadIdx.x;
    int isf32 = flag[0];
    qs[t] = LX(x, isf32, (long)qrow(g) * DD + t);
    __syncthreads();
    int c = t >> 2, tl = t & 3;
    float s = 0.f;
    for (int u = 0; u < 64; u++) s += qs[tl * 64 + u] * pn[c * DD + tl * 64 + u];
    part[t] = s; __syncthreads();
    if (tl == 0) sims[c] = part[t] + part[t + 1] + part[t + 2] + part[t + 3];
    __syncthreads();
    if (t == 0) {
        float best = sims[0]; int bi = 0;
        for (int c2 = 1; c2 < 64; c2++)
            if (sims[c2] > best) { best = sims[c2]; bi = c2; }
        pre_max[g] = best * qInv[g];
        pre_label[g] = bi;
    }
}

// ---------- K3: adapted prototypes (normalized) ----------
__global__ __launch_bounds__(256) void adapt_proto_kernel(const void* x, const int* flag,
                                                          const float* __restrict__ proto,
                                                          const float* __restrict__ selfs,
                                                          const float* __restrict__ pre_max,
                                                          const int* __restrict__ pre_label,
                                                          float* apn) {
    __shared__ float red[256];
    int c = blockIdx.x, t = threadIdx.x;
    int isf32 = flag[0];
    float lm = -INFINITY;
    for (int g = t; g < NQ; g += 256)
        if (pre_label[g] == c) lm = fmaxf(lm, pre_max[g]);
    float m = fmaxf(blk_reduce_max(lm, red), selfs[c]);
    float ls = 0.f;
    for (int g = t; g < NQ; g += 256)
        if (pre_label[g] == c) ls += expf(pre_max[g] - m);
    float es = expf(selfs[c] - m);
    float Z = blk_reduce_sum(ls, red) + es;
    float acc = es * proto[c * DD + t];
    for (int g = 0; g < NQ; g++) {
        if (pre_label[g] == c)
            acc += expf(pre_max[g] - m) * LX(x, isf32, (long)qrow(g) * DD + t);
    }
    float ap = acc / Z;
    float n2 = blk_reduce_sum(ap * ap, red);
    apn[c * DD + t] = ap / sqrtf(n2);
}

// ---------- K4: fp32 VALU GEMM + per-row top-10 over a column half ----------
__global__ __launch_bounds__(256, 2) void simtopk_kernel(const void* x, const int* flag,
                                                         const float* __restrict__ qInv,
                                                         float* __restrict__ topv2,
                                                         int* __restrict__ topi2) {
    __shared__ __align__(16) float Atc[2][32][36];
    __shared__ __align__(16) float Btc[2][32][132];
    __shared__ float S[32][129];
    __shared__ float lv[32][KNB];
    __shared__ int   li[32][KNB];

    const int t = threadIdx.x;
    const int b = blockIdx.x;
    const int rb = b & 255;
    const int half = b >> 8;
    const int row0 = rb * 32;
    const int col0 = half * 4096;
    const int isf32 = flag[0];

    if (t < 32) {
        for (int s = 0; s < KNB; s++) { lv[t][s] = -INFINITY; li[t][s] = 0x7fffffff; }
    }

    const int tkk = t & 31;
    const int tq  = t >> 5;
    const int tr  = t >> 5;
    const int tc  = t & 31;

    float Ar[4], Br[16];
    {
        for (int u = 0; u < 4; u++)
            Ar[u] = LX(x, isf32, (long)qrow(row0 + tq + 8 * u) * DD + tkk);
        for (int u = 0; u < 16; u++)
            Br[u] = LX(x, isf32, (long)qrow(col0 + tq + 8 * u) * DD + tkk);
        for (int u = 0; u < 4; u++) Atc[0][tkk][tq + 8 * u] = Ar[u];
        for (int u = 0; u < 16; u++) Btc[0][tkk][tq + 8 * u] = Br[u];
    }
    __syncthreads();

    float acc[4][4];
    #pragma unroll
    for (int i = 0; i < 4; i++)
        #pragma unroll
        for (int j = 0; j < 4; j++) acc[i][j] = 0.f;

    const float ainv = (t < 32) ? qInv[row0 + t] : 0.f;

    for (int cc = 0; cc < 256; cc++) {
        const int cur = cc & 1;
        if (cc + 1 < 256) {
            const int ct2 = (cc + 1) >> 3, ch2 = (cc + 1) & 7;
            const int jb2 = col0 + ct2 * 128, kb2 = ch2 * 32;
            for (int u = 0; u < 4; u++)
                Ar[u] = LX(x, isf32, (long)qrow(row0 + tq + 8 * u) * DD + kb2 + tkk);
            for (int u = 0; u < 16; u++)
                Br[u] = LX(x, isf32, (long)qrow(jb2 + tq + 8 * u) * DD + kb2 + tkk);
        }
        #pragma unroll
        for (int kk = 0; kk < 32; kk++) {
            float4 a  = *(const float4*)&Atc[cur][kk][4 * tr];
            float4 bv = *(const float4*)&Btc[cur][kk][4 * tc];
            acc[0][0] += a.x * bv.x; acc[0][1] += a.x * bv.y; acc[0][2] += a.x * bv.z; acc[0][3] += a.x * bv.w;
            acc[1][0] += a.y * bv.x; acc[1][1] += a.y * bv.y; acc[1][2] += a.y * bv.z; acc[1][3] += a.y * bv.w;
            acc[2][0] += a.z * bv.x; acc[2][1] += a.z * bv.y; acc[2][2] += a.z * bv.z; acc[2][3] += a.z * bv.w;
            acc[3][0] += a.w * bv.x; acc[3][1] += a.w * bv.y; acc[3][2] += a.w * bv.z; acc[3][3] += a.w * bv.w;
        }
        if (cc + 1 < 256) {
            const int nxt = cur ^ 1;
            for (int u = 0; u < 4; u++) Atc[nxt][tkk][tq + 8 * u] = Ar[u];
            for (int u = 0; u < 16; u++) Btc[nxt][tkk][tq + 8 * u] = Br[u];
        }
        __syncthreads();
        if ((cc & 7) == 7) {
            #pragma unroll
            for (int i = 0; i < 4; i++)
                #pragma unroll
                for (int j = 0; j < 4; j++)
                    S[4 * tr + i][4 * tc + j] = acc[i][j];
            __syncthreads();
            if (t < 32) {
                const int jb = col0 + (cc >> 3) * 128;
                float* Lv = lv[t]; int* Li = li[t];
                for (int j = 0; j < 128; j++) {
                    float v = S[t][j] * ainv * qInv[jb + j];
                    if (v > Lv[KNB - 1]) {
                        int p = KNB - 1;
                        while (p > 0 && Lv[p - 1] < v) {
                            Lv[p] = Lv[p - 1]; Li[p] = Li[p - 1]; p--;
                        }
                        Lv[p] = v; Li[p] = jb + j;
                    }
                }
            }
            __syncthreads();
            #pragma unroll
            for (int i = 0; i < 4; i++)
                #pragma unroll
                for (int j = 0; j < 4; j++) acc[i][j] = 0.f;
        }
    }
    if (t < 32) {
        const int g = row0 + t;
        for (int s = 0; s < KNB; s++) {
            topv2[(g * 2 + half) * KNB + s] = lv[t][s];
            topi2[(g * 2 + half) * KNB + s] = li[t][s];
        }
    }
}

// ---------- K5: merge halves ----------
__global__ __launch_bounds__(256) void merge_kernel(const float* __restrict__ topv2,
                                                    const int* __restrict__ topi2,
                                                    float* topv, int* topi) {
    int r = blockIdx.x * 256 + threadIdx.x;
    if (r >= NQ) return;
    const float* va = topv2 + r * 2 * KNB;
    const int*   ia = topi2 + r * 2 * KNB;
    const float* vb = va + KNB;
    const int*   ib = ia + KNB;
    int pa = 0, pb = 0;
    for (int s = 0; s < KNB; s++) {
        float fa = va[pa], fb = vb[pb];
        bool takeA = (fa > fb) || (fa == fb && ia[pa] < ib[pb]);
        if (takeA) { topv[r * KNB + s] = fa; topi[r * KNB + s] = ia[pa]; pa++; }
        else       { topv[r * KNB + s] = fb; topi[r * KNB + s] = ib[pb]; pb++; }
    }
}

// ---------- K6: mutual-kNN softmax, adapted query, final cos sims (fp32 output!) ----------
__global__ __launch_bounds__(256) void final_kernel(const void* x, const int* flag,
                                                    const float* __restrict__ apn,
                                                    const float* __restrict__ topv,
                                                    const int* __restrict__ topi,
                                                    const void* tao_raw,
                                                    float* out) {
    __shared__ float tv[KNB]; __shared__ int ti[KNB]; __shared__ float w[KNB];
    __shared__ float aq[256]; __shared__ float red[256];
    int i = blockIdx.x, t = threadIdx.x;
    int isf32 = flag[0];
    if (t < KNB) { tv[t] = topv[i * KNB + t]; ti[t] = topi[i * KNB + t]; }
    __syncthreads();
    if (t < KNB) {
        int j = ti[t];
        bool mut = false;
        for (int s = 0; s < KNB; s++) mut = mut || (topi[j * KNB + s] == i);
        w[t] = mut ? tv[t] : -INFINITY;
    }
    __syncthreads();
    if (t == 0) {
        float m = -INFINITY;
        for (int s = 0; s < KNB; s++) m = fmaxf(m, w[s]);
        float e[KNB]; float Z = 0.f;
        for (int s = 0; s < KNB; s++) { e[s] = expf(w[s] - m); Z += e[s]; }
        for (int s = 0; s < KNB; s++) w[s] = e[s] / Z;
    }
    __syncthreads();
    float a = 0.f;
    for (int s = 0; s < KNB; s++) {
        float ws = w[s];
        if (ws != 0.f) a += ws * LX(x, isf32, (long)qrow(ti[s]) * DD + t);
    }
    aq[t] = a;
    float n2 = blk_reduce_sum(a * a, red);
    float inv = 1.f / sqrtf(n2);
    int c = t >> 2, tl = t & 3;
    float sdot = 0.f;
    for (int u = 0; u < 64; u++) sdot += aq[tl * 64 + u] * apn[c * DD + tl * 64 + u];
    red[t] = sdot; __syncthreads();
    if (tl == 0) {
        float sv = red[t] + red[t + 1] + red[t + 2] + red[t + 3];
        float tao = LX(tao_raw, isf32, 0);
        out[i * NCLS + c] = tao * sv * inv;
    }
}

// ---------- D1: brute-force diagnostics (regression guard) ----------
__global__ __launch_bounds__(256) void brute_kernel(const void* x, const int* flag,
                                                    const float* __restrict__ qInv,
                                                    const float* __restrict__ pre_max,
                                                    const float* __restrict__ apn,
                                                    const float* __restrict__ topv,
                                                    const int* __restrict__ topi,
                                                    float* bs, int* diag) {
    __shared__ int bad[256];
    int t = threadIdx.x;
    int isf32 = flag[0];
    for (int j = t; j < NQ; j += 256) {
        float dot = 0.f;
        long r0 = (long)qrow(0) * DD, rj = (long)qrow(j) * DD;
        for (int d = 0; d < DD; d++) dot += LX(x, isf32, r0 + d) * LX(x, isf32, rj + d);
        bs[j] = dot * qInv[0] * qInv[j];
    }
    int mybad = 0;
    for (int g = t; g < NQ; g += 256) {
        bool found = false;
        for (int s = 0; s < KNB; s++) found = found || (topi[g * KNB + s] == g);
        if (!found) mybad++;
    }
    bad[t] = mybad;
    __syncthreads();
    int B = 0;
    if (t == 0) for (int u = 0; u < 256; u++) B += bad[u];
    __syncthreads();
    int myp = 0;
    for (int g = t; g < NQ; g += 256) {
        float v = pre_max[g];
        if (!(v > 0.f && v <= 1.001f)) myp++;
    }
    bad[t] = myp;
    __syncthreads();
    if (t == 0) {
        int P = 0;
        for (int u = 0; u < 256; u++) P += bad[u];
        float bv[KNB]; int bi[KNB];
        for (int s = 0; s < KNB; s++) { bv[s] = -INFINITY; bi[s] = 0x7fffffff; }
        for (int j = 0; j < NQ; j++) {
            float v = bs[j];
            if (v > bv[KNB - 1]) {
                int p = KNB - 1;
                while (p > 0 && bv[p - 1] < v) { bv[p] = bv[p - 1]; bi[p] = bi[p - 1]; p--; }
                bv[p] = v; bi[p] = j;
            }
        }
        int G = 0; float gvmax = 0.f;
        for (int s = 0; s < KNB; s++) {
            bool found = false;
            for (int u = 0; u < KNB; u++) found = found || (topi[u] == bi[s]);
            if (!found) G++;
            gvmax = fmaxf(gvmax, fabsf(bv[s] - topv[s]));
        }
        float n2 = 0.f;
        for (int d = 0; d < DD; d++) n2 += apn[d] * apn[d];
        diag[0] = B;
        diag[1] = G;
        diag[2] = (gvmax > 0.01f) ? 1 : 0;
        diag[3] = (P > 0) ? 1 : 0;
        diag[4] = (fabsf(n2 - 1.f) > 0.01f) ? 1 : 0;
        diag[5] = isf32;
    }
}

// Sentinel: absmax decodes 2e6*N + 1e6*P + 1e5*min(B,3) + 1e4*min(G,9) + 1e3*gv + 100*isf32.
__global__ void sentinel_kernel(const int* diag, float* out) {
    if (threadIdx.x == 0 && blockIdx.x == 0) {
        int B = diag[0], G = diag[1], gv = diag[2], P = diag[3], N = diag[4], F = diag[5];
        float S = 2000000.f * (float)N
                + 1000000.f * (float)P
                +  100000.f * (float)(B > 3 ? 3 : B)
                +   10000.f * (float)(G > 9 ? 9 : G)
                +    1000.f * (float)gv;
        if (S != 0.f) out[0] = S + 100.f * (float)F;
    }
}

extern "C" void kernel_launch(void* const* d_in, const int* in_sizes, int n_in,
                              void* d_out, int out_size, void* d_ws, size_t ws_size,
                              hipStream_t stream) {
    (void)in_sizes; (void)n_in; (void)out_size;
    const void* x   = d_in[0];
    const void* tao = d_in[1];
    float* out = (float*)d_out;   // reference output dtype is float32

    char* ws = (char*)d_ws;
    size_t off = 0;
    auto carve = [&](size_t bytes) {
        void* p = ws + off;
        off = (off + bytes + 255) & ~(size_t)255;
        return p;
    };
    float* proto   = (float*)carve(NCLS * DD * 4);
    float* pn      = (float*)carve(NCLS * DD * 4);
    float* selfs   = (float*)carve(NCLS * 4);
    float* qInv    = (float*)carve(NQ * 4);
    float* pre_max = (float*)carve(NQ * 4);
    int*   pre_lab = (int*)carve(NQ * 4);
    float* apn     = (float*)carve(NCLS * DD * 4);
    float* topv2   = (float*)carve((size_t)NQ * 2 * KNB * 4);
    int*   topi2   = (int*)carve((size_t)NQ * 2 * KNB * 4);
    float* topv    = (float*)carve((size_t)NQ * KNB * 4);
    int*   topi    = (int*)carve((size_t)NQ * KNB * 4);
    float* bs      = (float*)carve(NQ * 4);
    int*   diag    = (int*)carve(256);
    int*   flag    = (int*)carve(64);
    if (off > ws_size) return;

    detect_kernel<<<1, 64, 0, stream>>>((const unsigned short*)x, flag);
    qinv_kernel<<<NQ, 256, 0, stream>>>(x, flag, qInv);
    proto_kernel<<<NCLS, 256, 0, stream>>>(x, flag, proto, pn, selfs);
    presim_kernel<<<NQ, 256, 0, stream>>>(x, flag, qInv, pn, pre_max, pre_lab);
    adapt_proto_kernel<<<NCLS, 256, 0, stream>>>(x, flag, proto, selfs, pre_max, pre_lab, apn);
    simtopk_kernel<<<512, 256, 0, stream>>>(x, flag, qInv, topv2, topi2);
    merge_kernel<<<NQ / 256, 256, 0, stream>>>(topv2, topi2, topv, topi);
    final_kernel<<<NQ, 256, 0, stream>>>(x, flag, apn, topv, topi, tao, out);
    brute_kernel<<<1, 256, 0, stream>>>(x, flag, qInv, pre_max, apn, topv, topi, bs, diag);
    sentinel_kernel<<<1, 64, 0, stream>>>(diag, out);
}

// Round 9
// 1702.207 us; speedup vs baseline: 6.8610x; 6.8610x over previous
//
#include <hip/hip_runtime.h>
#include <math.h>

#define NCLS 64
#define KS 5
#define DD 256
#define NQ 8192   // NCLS*128
#define KNB 10

// row index in x (fp32 row units) of query g
__device__ __forceinline__ int qrow(int g) { return (g >> 7) * 133 + KS + (g & 127); }

__device__ __forceinline__ float blk_reduce_sum(float v, float* red) {
    int t = threadIdx.x;
    red[t] = v; __syncthreads();
    for (int off = 128; off > 0; off >>= 1) {
        if (t < off) red[t] += red[t + off];
        __syncthreads();
    }
    float r = red[0];
    __syncthreads();
    return r;
}

__device__ __forceinline__ float blk_reduce_max(float v, float* red) {
    int t = threadIdx.x;
    red[t] = v; __syncthreads();
    for (int off = 128; off > 0; off >>= 1) {
        if (t < off) red[t] = fmaxf(red[t], red[t + off]);
        __syncthreads();
    }
    float r = red[0];
    __syncthreads();
    return r;
}

// ---------- K0: qInv[g] = 1/||query_g|| ----------
__global__ __launch_bounds__(256) void qinv_kernel(const float* __restrict__ x,
                                                   float* __restrict__ qInv) {
    __shared__ float red[256];
    int g = blockIdx.x, t = threadIdx.x;
    float v = x[(long)qrow(g) * DD + t];
    float n2 = blk_reduce_sum(v * v, red);
    if (t == 0) qInv[g] = 1.f / sqrtf(n2);
}

// ---------- K1: proto, pn, self_sim ----------
__global__ __launch_bounds__(256) void proto_kernel(const float* __restrict__ x,
                                                    float* proto, float* pn, float* selfs) {
    __shared__ float red[256];
    int c = blockIdx.x, t = threadIdx.x;
    float s = 0.f;
    for (int j = 0; j < KS; j++) s += x[(long)(c * 133 + j) * DD + t];
    float p = s / 5.0f;
    proto[c * DD + t] = p;
    float n2 = blk_reduce_sum(p * p, red);
    float pv = p / sqrtf(n2);
    pn[c * DD + t] = pv;
    float ss = blk_reduce_sum(pv * pv, red);
    if (t == 0) selfs[c] = ss;
}

// ---------- K2: pre_sim argmax per query ----------
__global__ __launch_bounds__(256) void presim_kernel(const float* __restrict__ x,
                                                     const float* __restrict__ qInv,
                                                     const float* __restrict__ pn,
                                                     float* pre_max, int* pre_label) {
    __shared__ float qs[256];
    __shared__ float part[256];
    __shared__ float sims[64];
    int g = blockIdx.x, t = threadIdx.x;
    qs[t] = x[(long)qrow(g) * DD + t];
    __syncthreads();
    int c = t >> 2, tl = t & 3;
    float s = 0.f;
    for (int u = 0; u < 64; u++) s += qs[tl * 64 + u] * pn[c * DD + tl * 64 + u];
    part[t] = s; __syncthreads();
    if (tl == 0) sims[c] = part[t] + part[t + 1] + part[t + 2] + part[t + 3];
    __syncthreads();
    if (t == 0) {
        float best = sims[0]; int bi = 0;
        for (int c2 = 1; c2 < 64; c2++)
            if (sims[c2] > best) { best = sims[c2]; bi = c2; }
        pre_max[g] = best * qInv[g];
        pre_label[g] = bi;
    }
}

// ---------- K3: adapted prototypes (normalized) ----------
__global__ __launch_bounds__(256) void adapt_proto_kernel(const float* __restrict__ x,
                                                          const float* __restrict__ proto,
                                                          const float* __restrict__ selfs,
                                                          const float* __restrict__ pre_max,
                                                          const int* __restrict__ pre_label,
                                                          float* apn) {
    __shared__ float red[256];
    int c = blockIdx.x, t = threadIdx.x;
    float lm = -INFINITY;
    for (int g = t; g < NQ; g += 256)
        if (pre_label[g] == c) lm = fmaxf(lm, pre_max[g]);
    float m = fmaxf(blk_reduce_max(lm, red), selfs[c]);
    float ls = 0.f;
    for (int g = t; g < NQ; g += 256)
        if (pre_label[g] == c) ls += expf(pre_max[g] - m);
    float es = expf(selfs[c] - m);
    float Z = blk_reduce_sum(ls, red) + es;
    float acc = es * proto[c * DD + t];
    for (int g = 0; g < NQ; g++) {   // uniform branch across block
        if (pre_label[g] == c)
            acc += expf(pre_max[g] - m) * x[(long)qrow(g) * DD + t];
    }
    float ap = acc / Z;
    float n2 = blk_reduce_sum(ap * ap, red);
    apn[c * DD + t] = ap / sqrtf(n2);
}

// ---------- K4: fp32 GEMM + per-row top-10, spill-free ----------
// Block: 32 rows x 4096 cols (one half). Col-tiles of 128, K-chunks of 64.
// Single-buffered LDS staging: NO registers live across barriers.
__global__ __launch_bounds__(256, 2) void simtopk_kernel(const float* __restrict__ x,
                                                         const float* __restrict__ qInv,
                                                         float* __restrict__ topv2,
                                                         int* __restrict__ topi2) {
    __shared__ __align__(16) float Atc[64][36];    // [k][row]  9.2 KB
    __shared__ __align__(16) float Btc[64][132];   // [k][col] 33.8 KB
    __shared__ float S[32][129];                   // 16.5 KB
    __shared__ float lv[32][KNB];
    __shared__ int   li[32][KNB];                  // total ~62 KB -> 2 blocks/CU

    const int t = threadIdx.x;
    const int b = blockIdx.x;
    const int rb = b & 255;
    const int half = b >> 8;
    const int row0 = rb * 32;
    const int col0 = half * 4096;

    if (t < 32) {
        for (int s = 0; s < KNB; s++) { lv[t][s] = -INFINITY; li[t][s] = 0x7fffffff; }
    }

    const int tr = t >> 5;          // row-group (4 rows)
    const int tc = t & 31;          // col-group (4 cols)
    const int srow = t >> 3;        // staging row 0..31 (8 threads per row)
    const int sc4 = t & 7;          // staging float4 slot within 32-float span

    const float ainv = (t < 32) ? qInv[row0 + t] : 0.f;
    float thr = -INFINITY;

    const long arow = (long)qrow(row0 + srow) * DD;

    float acc[4][4];
    #pragma unroll
    for (int i = 0; i < 4; i++)
        #pragma unroll
        for (int j = 0; j < 4; j++) acc[i][j] = 0.f;

    for (int ct = 0; ct < 32; ct++) {          // 32 col-tiles of 128
        const int jb = col0 + ct * 128;
        for (int ch = 0; ch < 4; ch++) {       // 4 K-chunks of 64
            const int kb = ch * 64;
            __syncthreads();   // previous compute/scan done before LDS overwrite
            // stage A: 32 rows x 64 k (2 float4 per thread, consumed immediately)
            #pragma unroll
            for (int u = 0; u < 2; u++) {
                const int k0 = sc4 * 4 + 32 * u;
                float4 v = *(const float4*)(x + arow + kb + k0);
                Atc[k0 + 0][srow] = v.x;
                Atc[k0 + 1][srow] = v.y;
                Atc[k0 + 2][srow] = v.z;
                Atc[k0 + 3][srow] = v.w;
            }
            // stage B: 128 cols x 64 k (8 float4 per thread)
            #pragma unroll
            for (int u = 0; u < 4; u++) {
                const int bcol = srow + 32 * u;
                const long brow = (long)qrow(jb + bcol) * DD + kb;
                #pragma unroll
                for (int w = 0; w < 2; w++) {
                    const int k0 = sc4 * 4 + 32 * w;
                    float4 v = *(const float4*)(x + brow + k0);
                    Btc[k0 + 0][bcol] = v.x;
                    Btc[k0 + 1][bcol] = v.y;
                    Btc[k0 + 2][bcol] = v.z;
                    Btc[k0 + 3][bcol] = v.w;
                }
            }
            __syncthreads();
            #pragma unroll 16
            for (int kk = 0; kk < 64; kk++) {
                float4 a  = *(const float4*)&Atc[kk][4 * tr];
                float4 bv = *(const float4*)&Btc[kk][4 * tc];
                acc[0][0] += a.x * bv.x; acc[0][1] += a.x * bv.y; acc[0][2] += a.x * bv.z; acc[0][3] += a.x * bv.w;
                acc[1][0] += a.y * bv.x; acc[1][1] += a.y * bv.y; acc[1][2] += a.y * bv.z; acc[1][3] += a.y * bv.w;
                acc[2][0] += a.z * bv.x; acc[2][1] += a.z * bv.y; acc[2][2] += a.z * bv.z; acc[2][3] += a.z * bv.w;
                acc[3][0] += a.w * bv.x; acc[3][1] += a.w * bv.y; acc[3][2] += a.w * bv.z; acc[3][3] += a.w * bv.w;
            }
        }
        // col-tile complete: publish scores, scan, reset
        #pragma unroll
        for (int i = 0; i < 4; i++)
            #pragma unroll
            for (int j = 0; j < 4; j++)
                S[4 * tr + i][4 * tc + j] = acc[i][j];
        __syncthreads();
        if (t < 32) {
            float* Lv = lv[t]; int* Li = li[t];
            for (int j = 0; j < 128; j++) {
                float v = S[t][j] * ainv * qInv[jb + j];
                if (v > thr) {
                    int p = KNB - 1;
                    while (p > 0 && Lv[p - 1] < v) {
                        Lv[p] = Lv[p - 1]; Li[p] = Li[p - 1]; p--;
                    }
                    Lv[p] = v; Li[p] = jb + j;
                    thr = Lv[KNB - 1];
                }
            }
        }
        #pragma unroll
        for (int i = 0; i < 4; i++)
            #pragma unroll
            for (int j = 0; j < 4; j++) acc[i][j] = 0.f;
    }
    __syncthreads();
    if (t < 32) {
        const int g = row0 + t;
        for (int s = 0; s < KNB; s++) {
            topv2[(g * 2 + half) * KNB + s] = lv[t][s];
            topi2[(g * 2 + half) * KNB + s] = li[t][s];
        }
    }
}

// ---------- K5: merge halves ----------
__global__ __launch_bounds__(256) void merge_kernel(const float* __restrict__ topv2,
                                                    const int* __restrict__ topi2,
                                                    float* topv, int* topi) {
    int r = blockIdx.x * 256 + threadIdx.x;
    if (r >= NQ) return;
    const float* va = topv2 + r * 2 * KNB;
    const int*   ia = topi2 + r * 2 * KNB;
    const float* vb = va + KNB;
    const int*   ib = ia + KNB;
    int pa = 0, pb = 0;
    for (int s = 0; s < KNB; s++) {
        float fa = va[pa], fb = vb[pb];
        bool takeA = (fa > fb) || (fa == fb && ia[pa] < ib[pb]);
        if (takeA) { topv[r * KNB + s] = fa; topi[r * KNB + s] = ia[pa]; pa++; }
        else       { topv[r * KNB + s] = fb; topi[r * KNB + s] = ib[pb]; pb++; }
    }
}

// ---------- K6: mutual-kNN softmax, adapted query, final cos sims ----------
__global__ __launch_bounds__(256) void final_kernel(const float* __restrict__ x,
                                                    const float* __restrict__ apn,
                                                    const float* __restrict__ topv,
                                                    const int* __restrict__ topi,
                                                    const float* __restrict__ tao_raw,
                                                    float* out) {
    __shared__ float tv[KNB]; __shared__ int ti[KNB]; __shared__ float w[KNB];
    __shared__ float aq[256]; __shared__ float red[256];
    int i = blockIdx.x, t = threadIdx.x;
    if (t < KNB) { tv[t] = topv[i * KNB + t]; ti[t] = topi[i * KNB + t]; }
    __syncthreads();
    if (t < KNB) {
        int j = ti[t];
        bool mut = false;
        for (int s = 0; s < KNB; s++) mut = mut || (topi[j * KNB + s] == i);
        w[t] = mut ? tv[t] : -INFINITY;
    }
    __syncthreads();
    if (t == 0) {
        float m = -INFINITY;
        for (int s = 0; s < KNB; s++) m = fmaxf(m, w[s]);
        float e[KNB]; float Z = 0.f;
        for (int s = 0; s < KNB; s++) { e[s] = expf(w[s] - m); Z += e[s]; }
        for (int s = 0; s < KNB; s++) w[s] = e[s] / Z;
    }
    __syncthreads();
    float a = 0.f;
    for (int s = 0; s < KNB; s++) {
        float ws = w[s];
        if (ws != 0.f) a += ws * x[(long)qrow(ti[s]) * DD + t];
    }
    aq[t] = a;
    float n2 = blk_reduce_sum(a * a, red);
    float inv = 1.f / sqrtf(n2);
    int c = t >> 2, tl = t & 3;
    float sdot = 0.f;
    for (int u = 0; u < 64; u++) sdot += aq[tl * 64 + u] * apn[c * DD + tl * 64 + u];
    red[t] = sdot; __syncthreads();
    if (tl == 0) {
        float sv = red[t] + red[t + 1] + red[t + 2] + red[t + 3];
        out[i * NCLS + c] = tao_raw[0] * sv * inv;
    }
}

extern "C" void kernel_launch(void* const* d_in, const int* in_sizes, int n_in,
                              void* d_out, int out_size, void* d_ws, size_t ws_size,
                              hipStream_t stream) {
    (void)in_sizes; (void)n_in; (void)out_size;
    const float* x   = (const float*)d_in[0];
    const float* tao = (const float*)d_in[1];
    float* out = (float*)d_out;

    char* ws = (char*)d_ws;
    size_t off = 0;
    auto carve = [&](size_t bytes) {
        void* p = ws + off;
        off = (off + bytes + 255) & ~(size_t)255;
        return p;
    };
    float* proto   = (float*)carve(NCLS * DD * 4);
    float* pn      = (float*)carve(NCLS * DD * 4);
    float* selfs   = (float*)carve(NCLS * 4);
    float* qInv    = (float*)carve(NQ * 4);
    float* pre_max = (float*)carve(NQ * 4);
    int*   pre_lab = (int*)carve(NQ * 4);
    float* apn     = (float*)carve(NCLS * DD * 4);
    float* topv2   = (float*)carve((size_t)NQ * 2 * KNB * 4);
    int*   topi2   = (int*)carve((size_t)NQ * 2 * KNB * 4);
    float* topv    = (float*)carve((size_t)NQ * KNB * 4);
    int*   topi    = (int*)carve((size_t)NQ * KNB * 4);
    if (off > ws_size) return;

    qinv_kernel<<<NQ, 256, 0, stream>>>(x, qInv);
    proto_kernel<<<NCLS, 256, 0, stream>>>(x, proto, pn, selfs);
    presim_kernel<<<NQ, 256, 0, stream>>>(x, qInv, pn, pre_max, pre_lab);
    adapt_proto_kernel<<<NCLS, 256, 0, stream>>>(x, proto, selfs, pre_max, pre_lab, apn);
    simtopk_kernel<<<512, 256, 0, stream>>>(x, qInv, topv2, topi2);
    merge_kernel<<<NQ / 256, 256, 0, stream>>>(topv2, topi2, topv, topi);
    final_kernel<<<NQ, 256, 0, stream>>>(x, apn, topv, topi, tao, out);
}

// Round 10
// 1525.393 us; speedup vs baseline: 7.6563x; 1.1159x over previous
//
#include <hip/hip_runtime.h>
#include <math.h>

#define NCLS 64
#define KS 5
#define DD 256
#define NQ 8192   // NCLS*128
#define KNB 10

// row index in x (fp32 row units) of query g
__device__ __forceinline__ int qrow(int g) { return (g >> 7) * 133 + KS + (g & 127); }

__device__ __forceinline__ float blk_reduce_sum(float v, float* red) {
    int t = threadIdx.x;
    red[t] = v; __syncthreads();
    for (int off = 128; off > 0; off >>= 1) {
        if (t < off) red[t] += red[t + off];
        __syncthreads();
    }
    float r = red[0];
    __syncthreads();
    return r;
}

__device__ __forceinline__ float blk_reduce_max(float v, float* red) {
    int t = threadIdx.x;
    red[t] = v; __syncthreads();
    for (int off = 128; off > 0; off >>= 1) {
        if (t < off) red[t] = fmaxf(red[t], red[t + off]);
        __syncthreads();
    }
    float r = red[0];
    __syncthreads();
    return r;
}

// ---------- K0: qInv[g] = 1/||query_g|| ----------
__global__ __launch_bounds__(256) void qinv_kernel(const float* __restrict__ x,
                                                   float* __restrict__ qInv) {
    __shared__ float red[256];
    int g = blockIdx.x, t = threadIdx.x;
    float v = x[(long)qrow(g) * DD + t];
    float n2 = blk_reduce_sum(v * v, red);
    if (t == 0) qInv[g] = 1.f / sqrtf(n2);
}

// ---------- K1: proto, pn, self_sim ----------
__global__ __launch_bounds__(256) void proto_kernel(const float* __restrict__ x,
                                                    float* proto, float* pn, float* selfs) {
    __shared__ float red[256];
    int c = blockIdx.x, t = threadIdx.x;
    float s = 0.f;
    for (int j = 0; j < KS; j++) s += x[(long)(c * 133 + j) * DD + t];
    float p = s / 5.0f;
    proto[c * DD + t] = p;
    float n2 = blk_reduce_sum(p * p, red);
    float pv = p / sqrtf(n2);
    pn[c * DD + t] = pv;
    float ss = blk_reduce_sum(pv * pv, red);
    if (t == 0) selfs[c] = ss;
}

// ---------- K2: pre_sim argmax per query ----------
__global__ __launch_bounds__(256) void presim_kernel(const float* __restrict__ x,
                                                     const float* __restrict__ qInv,
                                                     const float* __restrict__ pn,
                                                     float* pre_max, int* pre_label) {
    __shared__ float qs[256];
    __shared__ float part[256];
    __shared__ float sims[64];
    int g = blockIdx.x, t = threadIdx.x;
    qs[t] = x[(long)qrow(g) * DD + t];
    __syncthreads();
    int c = t >> 2, tl = t & 3;
    float s = 0.f;
    for (int u = 0; u < 64; u++) s += qs[tl * 64 + u] * pn[c * DD + tl * 64 + u];
    part[t] = s; __syncthreads();
    if (tl == 0) sims[c] = part[t] + part[t + 1] + part[t + 2] + part[t + 3];
    __syncthreads();
    if (t == 0) {
        float best = sims[0]; int bi = 0;
        for (int c2 = 1; c2 < 64; c2++)
            if (sims[c2] > best) { best = sims[c2]; bi = c2; }
        pre_max[g] = best * qInv[g];
        pre_label[g] = bi;
    }
}

// ---------- K3: adapted prototypes (normalized) ----------
__global__ __launch_bounds__(256) void adapt_proto_kernel(const float* __restrict__ x,
                                                          const float* __restrict__ proto,
                                                          const float* __restrict__ selfs,
                                                          const float* __restrict__ pre_max,
                                                          const int* __restrict__ pre_label,
                                                          float* apn) {
    __shared__ float red[256];
    int c = blockIdx.x, t = threadIdx.x;
    float lm = -INFINITY;
    for (int g = t; g < NQ; g += 256)
        if (pre_label[g] == c) lm = fmaxf(lm, pre_max[g]);
    float m = fmaxf(blk_reduce_max(lm, red), selfs[c]);
    float ls = 0.f;
    for (int g = t; g < NQ; g += 256)
        if (pre_label[g] == c) ls += expf(pre_max[g] - m);
    float es = expf(selfs[c] - m);
    float Z = blk_reduce_sum(ls, red) + es;
    float acc = es * proto[c * DD + t];
    for (int g = 0; g < NQ; g++) {   // uniform branch across block
        if (pre_label[g] == c)
            acc += expf(pre_max[g] - m) * x[(long)qrow(g) * DD + t];
    }
    float ap = acc / Z;
    float n2 = blk_reduce_sum(ap * ap, red);
    apn[c * DD + t] = ap / sqrtf(n2);
}

// ---------- K4: fp32 GEMM + per-row top-10, 8x8 micro-tile, spill-free ----------
// Block: 64 rows x 2048 cols (one quarter). Col-tiles of 256, K-chunks of 32.
// LDS ~79.3 KB -> 2 blocks/CU. No registers live across barriers.
__global__ __launch_bounds__(256, 2) void simtopk_kernel(const float* __restrict__ x,
                                                         const float* __restrict__ qInv,
                                                         float* __restrict__ topv4,
                                                         int* __restrict__ topi4) {
    __shared__ __align__(16) float Atc[32][72];    // [k][row]   9.2 KB
    __shared__ __align__(16) float Btc[32][264];   // [k][col]  33.8 KB
    __shared__ float S[64][129];                   // 33.0 KB (stride 129: scan 2-way = free)
    __shared__ float lv[64][KNB];
    __shared__ int   li[64][KNB];                  // 5.1 KB

    const int t = threadIdx.x;
    const int b = blockIdx.x;
    const int rb = b >> 2;          // 128 row stripes of 64
    const int qt = b & 3;           // column quarter
    const int row0 = rb * 64;
    const int col0 = qt * 2048;

    const int tr = t >> 5;          // 0..7: owns rows 8tr..8tr+7
    const int tc = t & 31;          // 0..31: owns cols 8tc..8tc+7

    const int srowA = t >> 2;       // A staging: 0..63
    const int sk4A  = t & 3;        // 0..3
    const int scB   = t >> 3;       // B staging col group: 0..31
    const int skB   = t & 7;        // 0..7

    if (t < 64) {
        for (int s = 0; s < KNB; s++) { lv[t][s] = -INFINITY; li[t][s] = 0x7fffffff; }
    }
    const float ainv = (t < 64) ? qInv[row0 + t] : 0.f;
    float thr = -INFINITY;

    const long arow = (long)qrow(row0 + srowA) * DD;

    float acc[8][8];

    for (int ct = 0; ct < 8; ct++) {            // 8 col-tiles of 256
        const int jb = col0 + ct * 256;
        #pragma unroll
        for (int i = 0; i < 8; i++)
            #pragma unroll
            for (int j = 0; j < 8; j++) acc[i][j] = 0.f;

        for (int ch = 0; ch < 8; ch++) {        // 8 K-chunks of 32
            const int kb = ch * 32;
            __syncthreads();   // previous compute/scan done before LDS overwrite
            // stage A: 64 rows x 32 k (2 float4/thread, consumed immediately)
            {
                const int k0 = sk4A * 8;
                float4 v0 = *(const float4*)(x + arow + kb + k0);
                float4 v1 = *(const float4*)(x + arow + kb + k0 + 4);
                Atc[k0 + 0][srowA] = v0.x; Atc[k0 + 1][srowA] = v0.y;
                Atc[k0 + 2][srowA] = v0.z; Atc[k0 + 3][srowA] = v0.w;
                Atc[k0 + 4][srowA] = v1.x; Atc[k0 + 5][srowA] = v1.y;
                Atc[k0 + 6][srowA] = v1.z; Atc[k0 + 7][srowA] = v1.w;
            }
            // stage B: 256 cols x 32 k (8 float4/thread)
            #pragma unroll
            for (int u = 0; u < 8; u++) {
                const int bcol = scB + 32 * u;
                const int k0 = skB * 4;
                float4 v = *(const float4*)(x + (long)qrow(jb + bcol) * DD + kb + k0);
                Btc[k0 + 0][bcol] = v.x; Btc[k0 + 1][bcol] = v.y;
                Btc[k0 + 2][bcol] = v.z; Btc[k0 + 3][bcol] = v.w;
            }
            __syncthreads();
            #pragma unroll 4
            for (int kk = 0; kk < 32; kk++) {
                float4 a0 = *(const float4*)&Atc[kk][8 * tr];
                float4 a1 = *(const float4*)&Atc[kk][8 * tr + 4];
                float4 b0 = *(const float4*)&Btc[kk][8 * tc];
                float4 b1 = *(const float4*)&Btc[kk][8 * tc + 4];
                float av[8] = {a0.x, a0.y, a0.z, a0.w, a1.x, a1.y, a1.z, a1.w};
                float bv[8] = {b0.x, b0.y, b0.z, b0.w, b1.x, b1.y, b1.z, b1.w};
                #pragma unroll
                for (int i = 0; i < 8; i++)
                    #pragma unroll
                    for (int j = 0; j < 8; j++)
                        acc[i][j] += av[i] * bv[j];
            }
        }
        // publish + scan in two 64x128 chunks
        for (int h = 0; h < 2; h++) {
            __syncthreads();
            if ((tc >> 4) == h) {
                const int cb = 8 * (tc & 15);
                #pragma unroll
                for (int i = 0; i < 8; i++)
                    #pragma unroll
                    for (int j = 0; j < 8; j++)
                        S[8 * tr + i][cb + j] = acc[i][j];
            }
            __syncthreads();
            if (t < 64) {
                const int jg0 = jb + 128 * h;
                float* Lv = lv[t]; int* Li = li[t];
                for (int j = 0; j < 128; j++) {
                    float v = S[t][j] * ainv * qInv[jg0 + j];
                    if (v > thr) {
                        int p = KNB - 1;
                        while (p > 0 && Lv[p - 1] < v) {
                            Lv[p] = Lv[p - 1]; Li[p] = Li[p - 1]; p--;
                        }
                        Lv[p] = v; Li[p] = jg0 + j;
                        thr = Lv[KNB - 1];
                    }
                }
            }
        }
    }
    __syncthreads();
    if (t < 64) {
        const int g = row0 + t;
        for (int s = 0; s < KNB; s++) {
            topv4[(g * 4 + qt) * KNB + s] = lv[t][s];
            topi4[(g * 4 + qt) * KNB + s] = li[t][s];
        }
    }
}

// ---------- K5: 4-way merge of quarter lists ----------
__global__ __launch_bounds__(256) void merge_kernel(const float* __restrict__ topv4,
                                                    const int* __restrict__ topi4,
                                                    float* topv, int* topi) {
    int r = blockIdx.x * 256 + threadIdx.x;
    if (r >= NQ) return;
    int pos[4] = {0, 0, 0, 0};
    for (int s = 0; s < KNB; s++) {
        float bvv = -INFINITY; int bii = 0x7fffffff; int bw = 0;
        #pragma unroll
        for (int w = 0; w < 4; w++) {
            if (pos[w] < KNB) {
                float cv = topv4[(r * 4 + w) * KNB + pos[w]];
                int   ci = topi4[(r * 4 + w) * KNB + pos[w]];
                if (cv > bvv || (cv == bvv && ci < bii)) { bw = w; bvv = cv; bii = ci; }
            }
        }
        pos[bw]++;
        topv[r * KNB + s] = bvv;
        topi[r * KNB + s] = bii;
    }
}

// ---------- K6: mutual-kNN softmax, adapted query, final cos sims ----------
__global__ __launch_bounds__(256) void final_kernel(const float* __restrict__ x,
                                                    const float* __restrict__ apn,
                                                    const float* __restrict__ topv,
                                                    const int* __restrict__ topi,
                                                    const float* __restrict__ tao_raw,
                                                    float* out) {
    __shared__ float tv[KNB]; __shared__ int ti[KNB]; __shared__ float w[KNB];
    __shared__ float aq[256]; __shared__ float red[256];
    int i = blockIdx.x, t = threadIdx.x;
    if (t < KNB) { tv[t] = topv[i * KNB + t]; ti[t] = topi[i * KNB + t]; }
    __syncthreads();
    if (t < KNB) {
        int j = ti[t];
        bool mut = false;
        for (int s = 0; s < KNB; s++) mut = mut || (topi[j * KNB + s] == i);
        w[t] = mut ? tv[t] : -INFINITY;
    }
    __syncthreads();
    if (t == 0) {
        float m = -INFINITY;
        for (int s = 0; s < KNB; s++) m = fmaxf(m, w[s]);
        float e[KNB]; float Z = 0.f;
        for (int s = 0; s < KNB; s++) { e[s] = expf(w[s] - m); Z += e[s]; }
        for (int s = 0; s < KNB; s++) w[s] = e[s] / Z;
    }
    __syncthreads();
    float a = 0.f;
    for (int s = 0; s < KNB; s++) {
        float ws = w[s];
        if (ws != 0.f) a += ws * x[(long)qrow(ti[s]) * DD + t];
    }
    aq[t] = a;
    float n2 = blk_reduce_sum(a * a, red);
    float inv = 1.f / sqrtf(n2);
    int c = t >> 2, tl = t & 3;
    float sdot = 0.f;
    for (int u = 0; u < 64; u++) sdot += aq[tl * 64 + u] * apn[c * DD + tl * 64 + u];
    red[t] = sdot; __syncthreads();
    if (tl == 0) {
        float sv = red[t] + red[t + 1] + red[t + 2] + red[t + 3];
        out[i * NCLS + c] = tao_raw[0] * sv * inv;
    }
}

extern "C" void kernel_launch(void* const* d_in, const int* in_sizes, int n_in,
                              void* d_out, int out_size, void* d_ws, size_t ws_size,
                              hipStream_t stream) {
    (void)in_sizes; (void)n_in; (void)out_size;
    const float* x   = (const float*)d_in[0];
    const float* tao = (const float*)d_in[1];
    float* out = (float*)d_out;

    char* ws = (char*)d_ws;
    size_t off = 0;
    auto carve = [&](size_t bytes) {
        void* p = ws + off;
        off = (off + bytes + 255) & ~(size_t)255;
        return p;
    };
    float* proto   = (float*)carve(NCLS * DD * 4);
    float* pn      = (float*)carve(NCLS * DD * 4);
    float* selfs   = (float*)carve(NCLS * 4);
    float* qInv    = (float*)carve(NQ * 4);
    float* pre_max = (float*)carve(NQ * 4);
    int*   pre_lab = (int*)carve(NQ * 4);
    float* apn     = (float*)carve(NCLS * DD * 4);
    float* topv4   = (float*)carve((size_t)NQ * 4 * KNB * 4);
    int*   topi4   = (int*)carve((size_t)NQ * 4 * KNB * 4);
    float* topv    = (float*)carve((size_t)NQ * KNB * 4);
    int*   topi    = (int*)carve((size_t)NQ * KNB * 4);
    if (off > ws_size) return;

    qinv_kernel<<<NQ, 256, 0, stream>>>(x, qInv);
    proto_kernel<<<NCLS, 256, 0, stream>>>(x, proto, pn, selfs);
    presim_kernel<<<NQ, 256, 0, stream>>>(x, qInv, pn, pre_max, pre_lab);
    adapt_proto_kernel<<<NCLS, 256, 0, stream>>>(x, proto, selfs, pre_max, pre_lab, apn);
    simtopk_kernel<<<512, 256, 0, stream>>>(x, qInv, topv4, topi4);
    merge_kernel<<<NQ / 256, 256, 0, stream>>>(topv4, topi4, topv, topi);
    final_kernel<<<NQ, 256, 0, stream>>>(x, apn, topv, topi, tao, out);
}

// Round 11
// 1408.443 us; speedup vs baseline: 8.2920x; 1.0830x over previous
//
#include <hip/hip_runtime.h>
#include <math.h>

#define NCLS 64
#define KS 5
#define DD 256
#define NQ 8192   // NCLS*128
#define KNB 10

// row index in x (fp32 row units) of query g
__device__ __forceinline__ int qrow(int g) { return (g >> 7) * 133 + KS + (g & 127); }

__device__ __forceinline__ float blk_reduce_sum(float v, float* red) {
    int t = threadIdx.x;
    red[t] = v; __syncthreads();
    for (int off = 128; off > 0; off >>= 1) {
        if (t < off) red[t] += red[t + off];
        __syncthreads();
    }
    float r = red[0];
    __syncthreads();
    return r;
}

__device__ __forceinline__ float blk_reduce_max(float v, float* red) {
    int t = threadIdx.x;
    red[t] = v; __syncthreads();
    for (int off = 128; off > 0; off >>= 1) {
        if (t < off) red[t] = fmaxf(red[t], red[t + off]);
        __syncthreads();
    }
    float r = red[0];
    __syncthreads();
    return r;
}

// ---------- K1: proto, pn, self_sim ----------
__global__ __launch_bounds__(256) void proto_kernel(const float* __restrict__ x,
                                                    float* proto, float* pn, float* selfs) {
    __shared__ float red[256];
    int c = blockIdx.x, t = threadIdx.x;
    float s = 0.f;
    for (int j = 0; j < KS; j++) s += x[(long)(c * 133 + j) * DD + t];
    float p = s / 5.0f;
    proto[c * DD + t] = p;
    float n2 = blk_reduce_sum(p * p, red);
    float pv = p / sqrtf(n2);
    pn[c * DD + t] = pv;
    float ss = blk_reduce_sum(pv * pv, red);
    if (t == 0) selfs[c] = ss;
}

// ---------- K2: fused qInv + pre_sim argmax per query ----------
__global__ __launch_bounds__(256) void presim_kernel(const float* __restrict__ x,
                                                     const float* __restrict__ pn,
                                                     float* qInv,
                                                     float* pre_max, int* pre_label) {
    __shared__ float qs[256];
    __shared__ float part[256];
    __shared__ float sims[64];
    int g = blockIdx.x, t = threadIdx.x;
    float v = x[(long)qrow(g) * DD + t];
    qs[t] = v;
    float n2 = blk_reduce_sum(v * v, part);
    float qi = 1.f / sqrtf(n2);
    __syncthreads();
    int c = t >> 2, tl = t & 3;
    float s = 0.f;
    for (int u = 0; u < 64; u++) s += qs[tl * 64 + u] * pn[c * DD + tl * 64 + u];
    part[t] = s; __syncthreads();
    if (tl == 0) sims[c] = part[t] + part[t + 1] + part[t + 2] + part[t + 3];
    __syncthreads();
    if (t == 0) {
        float best = sims[0]; int bi = 0;
        for (int c2 = 1; c2 < 64; c2++)
            if (sims[c2] > best) { best = sims[c2]; bi = c2; }
        qInv[g] = qi;
        pre_max[g] = best * qi;
        pre_label[g] = bi;
    }
}

// ---------- K3: adapted prototypes (normalized) ----------
__global__ __launch_bounds__(256) void adapt_proto_kernel(const float* __restrict__ x,
                                                          const float* __restrict__ proto,
                                                          const float* __restrict__ selfs,
                                                          const float* __restrict__ pre_max,
                                                          const int* __restrict__ pre_label,
                                                          float* apn) {
    __shared__ float red[256];
    int c = blockIdx.x, t = threadIdx.x;
    float lm = -INFINITY;
    for (int g = t; g < NQ; g += 256)
        if (pre_label[g] == c) lm = fmaxf(lm, pre_max[g]);
    float m = fmaxf(blk_reduce_max(lm, red), selfs[c]);
    float ls = 0.f;
    for (int g = t; g < NQ; g += 256)
        if (pre_label[g] == c) ls += expf(pre_max[g] - m);
    float es = expf(selfs[c] - m);
    float Z = blk_reduce_sum(ls, red) + es;
    float acc = es * proto[c * DD + t];
    for (int g = 0; g < NQ; g++) {   // uniform branch across block
        if (pre_label[g] == c)
            acc += expf(pre_max[g] - m) * x[(long)qrow(g) * DD + t];
    }
    float ap = acc / Z;
    float n2 = blk_reduce_sum(ap * ap, red);
    apn[c * DD + t] = ap / sqrtf(n2);
}

// ---------- K4: fp32 GEMM + top-10; 8x8 tile, XOR-swizzled B, conflict-minimal ----------
// Block: 64 rows x 2048 cols (quarter). Col-tiles 256, K-chunks 32. LDS 80.1 KB -> 2 blocks/CU.
// Lane tc owns cols {4tc..4tc+3} and {128+4tc..+3}. B quad cq of k-row k stored at quad cq^((k>>2)&7).
__global__ __launch_bounds__(256, 2) void simtopk_kernel(const float* __restrict__ x,
                                                         const float* __restrict__ qInv,
                                                         float* __restrict__ topv4,
                                                         int* __restrict__ topi4) {
    __shared__ __align__(16) float Atc[32][72];     // [k][row]        9216 B
    __shared__ __align__(16) float Btc[32 * 256];   // swizzled [k][.] 32768 B
    __shared__ float S[64][129];                    // scores          33024 B
    __shared__ float lv[64][KNB];
    __shared__ int   li[64][KNB];                   // 5120 B

    const int t = threadIdx.x;
    const int b = blockIdx.x;
    const int rb = b >> 2;
    const int qt = b & 3;
    const int row0 = rb * 64;
    const int col0 = qt * 2048;

    const int tr = t >> 5;          // 0..7
    const int tc = t & 31;          // 0..31

    const int srowA = t >> 2;       // 0..63
    const int sk4A  = t & 3;        // 0..3
    const int scB   = t >> 3;       // 0..31
    const int skB   = t & 7;        // 0..7

    if (t < 64) {
        for (int s = 0; s < KNB; s++) { lv[t][s] = -INFINITY; li[t][s] = 0x7fffffff; }
    }
    const float ainv = (t < 64) ? qInv[row0 + t] : 0.f;
    float thr = -INFINITY;

    const long arow = (long)qrow(row0 + srowA) * DD;
    // B staging swizzle (constant per thread): col bcol=scB+32u, quad cq=bcol>>2, j=bcol&3,
    // k=4*skB+q -> s(k)=skB -> physical float = (4skB+q)*256 + 4*(cq^skB) + j
    const int bj = scB & 3;

    float acc[8][8];

    for (int ct = 0; ct < 8; ct++) {            // 8 col-tiles of 256
        const int jb = col0 + ct * 256;
        #pragma unroll
        for (int i = 0; i < 8; i++)
            #pragma unroll
            for (int j = 0; j < 8; j++) acc[i][j] = 0.f;

        for (int ch = 0; ch < 8; ch++) {        // 8 K-chunks of 32
            const int kb = ch * 32;
            __syncthreads();   // prior reads of Atc/Btc/S complete before overwrite
            // stage A: 64 rows x 32 k
            {
                const int k0 = sk4A * 8;
                float4 v0 = *(const float4*)(x + arow + kb + k0);
                float4 v1 = *(const float4*)(x + arow + kb + k0 + 4);
                Atc[k0 + 0][srowA] = v0.x; Atc[k0 + 1][srowA] = v0.y;
                Atc[k0 + 2][srowA] = v0.z; Atc[k0 + 3][srowA] = v0.w;
                Atc[k0 + 4][srowA] = v1.x; Atc[k0 + 5][srowA] = v1.y;
                Atc[k0 + 6][srowA] = v1.z; Atc[k0 + 7][srowA] = v1.w;
            }
            // stage B: 256 cols x 32 k, swizzled (staging writes 2-way = free)
            #pragma unroll
            for (int u = 0; u < 8; u++) {
                const int bcol = scB + 32 * u;
                const int cq = bcol >> 2;
                const int base = 4 * (cq ^ skB) + bj;
                float4 v = *(const float4*)(x + (long)qrow(jb + bcol) * DD + kb + 4 * skB);
                Btc[(4 * skB + 0) * 256 + base] = v.x;
                Btc[(4 * skB + 1) * 256 + base] = v.y;
                Btc[(4 * skB + 2) * 256 + base] = v.z;
                Btc[(4 * skB + 3) * 256 + base] = v.w;
            }
            __syncthreads();
            // compute: reads optimal (stride-4 b128 starts via XOR permutation)
            for (int k4 = 0; k4 < 8; k4++) {
                const float* Bk = Btc + (4 * k4) * 256 + 4 * (tc ^ k4);
                const float* Ak = &Atc[4 * k4][8 * tr];
                #pragma unroll
                for (int q = 0; q < 4; q++) {
                    float4 a0 = *(const float4*)(Ak + q * 72);
                    float4 a1 = *(const float4*)(Ak + q * 72 + 4);
                    float4 b0 = *(const float4*)(Bk + q * 256);
                    float4 b1 = *(const float4*)(Bk + q * 256 + 128);
                    float av[8] = {a0.x, a0.y, a0.z, a0.w, a1.x, a1.y, a1.z, a1.w};
                    float bv[8] = {b0.x, b0.y, b0.z, b0.w, b1.x, b1.y, b1.z, b1.w};
                    #pragma unroll
                    for (int i = 0; i < 8; i++)
                        #pragma unroll
                        for (int j = 0; j < 8; j++)
                            acc[i][j] += av[i] * bv[j];
                }
            }
        }
        // qInv for owned cols (fold into publish)
        float4 qj0 = *(const float4*)(qInv + jb + 4 * tc);
        float4 qj1 = *(const float4*)(qInv + jb + 128 + 4 * tc);
        float q0[4] = {qj0.x, qj0.y, qj0.z, qj0.w};
        float q1[4] = {qj1.x, qj1.y, qj1.z, qj1.w};
        // half 0: cols jb+0..127
        __syncthreads();
        #pragma unroll
        for (int i = 0; i < 8; i++)
            #pragma unroll
            for (int j = 0; j < 4; j++)
                S[8 * tr + i][4 * tc + j] = acc[i][j] * q0[j];
        __syncthreads();
        if (t < 64) {
            float* Lv = lv[t]; int* Li = li[t];
            const int jg0 = jb;
            for (int j = 0; j < 128; j++) {
                float v = S[t][j] * ainv;
                if (v > thr) {
                    int p = KNB - 1;
                    while (p > 0 && Lv[p - 1] < v) {
                        Lv[p] = Lv[p - 1]; Li[p] = Li[p - 1]; p--;
                    }
                    Lv[p] = v; Li[p] = jg0 + j;
                    thr = Lv[KNB - 1];
                }
            }
        }
        // half 1: cols jb+128..255
        __syncthreads();
        #pragma unroll
        for (int i = 0; i < 8; i++)
            #pragma unroll
            for (int j = 0; j < 4; j++)
                S[8 * tr + i][4 * tc + j] = acc[i][4 + j] * q1[j];
        __syncthreads();
        if (t < 64) {
            float* Lv = lv[t]; int* Li = li[t];
            const int jg0 = jb + 128;
            for (int j = 0; j < 128; j++) {
                float v = S[t][j] * ainv;
                if (v > thr) {
                    int p = KNB - 1;
                    while (p > 0 && Lv[p - 1] < v) {
                        Lv[p] = Lv[p - 1]; Li[p] = Li[p - 1]; p--;
                    }
                    Lv[p] = v; Li[p] = jg0 + j;
                    thr = Lv[KNB - 1];
                }
            }
        }
    }
    __syncthreads();
    if (t < 64) {
        const int g = row0 + t;
        for (int s = 0; s < KNB; s++) {
            topv4[(g * 4 + qt) * KNB + s] = lv[t][s];
            topi4[(g * 4 + qt) * KNB + s] = li[t][s];
        }
    }
}

// ---------- K5: 4-way merge of quarter lists ----------
__global__ __launch_bounds__(256) void merge_kernel(const float* __restrict__ topv4,
                                                    const int* __restrict__ topi4,
                                                    float* topv, int* topi) {
    int r = blockIdx.x * 256 + threadIdx.x;
    if (r >= NQ) return;
    int pos[4] = {0, 0, 0, 0};
    for (int s = 0; s < KNB; s++) {
        float bvv = -INFINITY; int bii = 0x7fffffff; int bw = 0;
        #pragma unroll
        for (int w = 0; w < 4; w++) {
            if (pos[w] < KNB) {
                float cv = topv4[(r * 4 + w) * KNB + pos[w]];
                int   ci = topi4[(r * 4 + w) * KNB + pos[w]];
                if (cv > bvv || (cv == bvv && ci < bii)) { bw = w; bvv = cv; bii = ci; }
            }
        }
        pos[bw]++;
        topv[r * KNB + s] = bvv;
        topi[r * KNB + s] = bii;
    }
}

// ---------- K6: mutual-kNN softmax, adapted query, final cos sims ----------
__global__ __launch_bounds__(256) void final_kernel(const float* __restrict__ x,
                                                    const float* __restrict__ apn,
                                                    const float* __restrict__ topv,
                                                    const int* __restrict__ topi,
                                                    const float* __restrict__ tao_raw,
                                                    float* out) {
    __shared__ float tv[KNB]; __shared__ int ti[KNB]; __shared__ float w[KNB];
    __shared__ float aq[256]; __shared__ float red[256];
    int i = blockIdx.x, t = threadIdx.x;
    if (t < KNB) { tv[t] = topv[i * KNB + t]; ti[t] = topi[i * KNB + t]; }
    __syncthreads();
    if (t < KNB) {
        int j = ti[t];
        bool mut = false;
        for (int s = 0; s < KNB; s++) mut = mut || (topi[j * KNB + s] == i);
        w[t] = mut ? tv[t] : -INFINITY;
    }
    __syncthreads();
    if (t == 0) {
        float m = -INFINITY;
        for (int s = 0; s < KNB; s++) m = fmaxf(m, w[s]);
        float e[KNB]; float Z = 0.f;
        for (int s = 0; s < KNB; s++) { e[s] = expf(w[s] - m); Z += e[s]; }
        for (int s = 0; s < KNB; s++) w[s] = e[s] / Z;
    }
    __syncthreads();
    float a = 0.f;
    for (int s = 0; s < KNB; s++) {
        float ws = w[s];
        if (ws != 0.f) a += ws * x[(long)qrow(ti[s]) * DD + t];
    }
    aq[t] = a;
    float n2 = blk_reduce_sum(a * a, red);
    float inv = 1.f / sqrtf(n2);
    int c = t >> 2, tl = t & 3;
    float sdot = 0.f;
    for (int u = 0; u < 64; u++) sdot += aq[tl * 64 + u] * apn[c * DD + tl * 64 + u];
    red[t] = sdot; __syncthreads();
    if (tl == 0) {
        float sv = red[t] + red[t + 1] + red[t + 2] + red[t + 3];
        out[i * NCLS + c] = tao_raw[0] * sv * inv;
    }
}

extern "C" void kernel_launch(void* const* d_in, const int* in_sizes, int n_in,
                              void* d_out, int out_size, void* d_ws, size_t ws_size,
                              hipStream_t stream) {
    (void)in_sizes; (void)n_in; (void)out_size;
    const float* x   = (const float*)d_in[0];
    const float* tao = (const float*)d_in[1];
    float* out = (float*)d_out;

    char* ws = (char*)d_ws;
    size_t off = 0;
    auto carve = [&](size_t bytes) {
        void* p = ws + off;
        off = (off + bytes + 255) & ~(size_t)255;
        return p;
    };
    float* proto   = (float*)carve(NCLS * DD * 4);
    float* pn      = (float*)carve(NCLS * DD * 4);
    float* selfs   = (float*)carve(NCLS * 4);
    float* qInv    = (float*)carve(NQ * 4);
    float* pre_max = (float*)carve(NQ * 4);
    int*   pre_lab = (int*)carve(NQ * 4);
    float* apn     = (float*)carve(NCLS * DD * 4);
    float* topv4   = (float*)carve((size_t)NQ * 4 * KNB * 4);
    int*   topi4   = (int*)carve((size_t)NQ * 4 * KNB * 4);
    float* topv    = (float*)carve((size_t)NQ * KNB * 4);
    int*   topi    = (int*)carve((size_t)NQ * KNB * 4);
    if (off > ws_size) return;

    proto_kernel<<<NCLS, 256, 0, stream>>>(x, proto, pn, selfs);
    presim_kernel<<<NQ, 256, 0, stream>>>(x, pn, qInv, pre_max, pre_lab);
    adapt_proto_kernel<<<NCLS, 256, 0, stream>>>(x, proto, selfs, pre_max, pre_lab, apn);
    simtopk_kernel<<<512, 256, 0, stream>>>(x, qInv, topv4, topi4);
    merge_kernel<<<NQ / 256, 256, 0, stream>>>(topv4, topi4, topv, topi);
    final_kernel<<<NQ, 256, 0, stream>>>(x, apn, topv, topi, tao, out);
}